// Round 1
// baseline (296.948 us; speedup 1.0000x reference)
//
#include <hip/hip_runtime.h>
#include <math.h>

#define N_D 128       // embedding dim (fixed by reference)
#define BI 64         // rows per block
#define BJ 64         // cols per tile
#define LSTRIDE 132   // padded LDS row stride (floats), keeps 16B align, breaks bank conflicts
#define NSPLIT 8      // column-range splits (parallelism: 128*8 = 1024 blocks)

// ws layout (floats): [0,N) sumexp | [N,2N) possum | [2N,3N) poscnt | [3N] int flag (1 => labels are int64)

__global__ void k_prep(const int* __restrict__ lab32, float* __restrict__ ws, int N) {
    int tid = blockIdx.x * blockDim.x + threadIdx.x;
    int total = 3 * N;
    for (int i = tid; i < total; i += gridDim.x * blockDim.x) ws[i] = 0.0f;
    if (blockIdx.x == 0) {
        __shared__ int nz;
        if (threadIdx.x == 0) nz = 0;
        __syncthreads();
        int local = 0;
        int half = N >> 1;
        for (int i = threadIdx.x; i < half; i += blockDim.x)
            if (lab32[2 * i + 1] != 0) local = 1;
        if (local) atomicOr(&nz, 1);
        __syncthreads();
        // labels 0..99: if buffer is int64 (LE), every odd 32-bit word is 0.
        if (threadIdx.x == 0) ((int*)ws)[3 * N] = (nz == 0) ? 1 : 0;
    }
}

__global__ __launch_bounds__(256) void k_main(const float* __restrict__ emb,
                                              const int* __restrict__ lab32,
                                              float* __restrict__ ws, int N) {
    __shared__ float Ash[BI][LSTRIDE];
    __shared__ float Bsh[BJ][LSTRIDE];
    __shared__ int labA[BI];
    __shared__ int labB[BJ];

    const int tid = threadIdx.x;
    const int tx = tid & 15;
    const int ty = tid >> 4;
    const int rowbase = blockIdx.x * BI;
    const int colsPer = N / NSPLIT;
    const int colstart = blockIdx.y * colsPer;
    const int flag64 = ((const int*)ws)[3 * N];

    // stage A tile (64 rows x 128 f32) via float4
    for (int i = tid; i < BI * (N_D / 4); i += 256) {
        int row = i >> 5;           // 32 float4 per row
        int kq = i & 31;
        *(float4*)&Ash[row][kq << 2] =
            *(const float4*)&emb[(size_t)(rowbase + row) * N_D + (kq << 2)];
    }
    if (tid < BI) {
        int g = rowbase + tid;
        labA[tid] = flag64 ? lab32[2 * g] : lab32[g];
    }
    __syncthreads();

    int labR[4];
    #pragma unroll
    for (int r = 0; r < 4; ++r) labR[r] = labA[ty + 16 * r];

    float se[4] = {0, 0, 0, 0}, ps[4] = {0, 0, 0, 0}, pc[4] = {0, 0, 0, 0};

    for (int jt = colstart; jt < colstart + colsPer; jt += BJ) {
        __syncthreads();   // everyone done with previous Bsh/labB
        for (int i = tid; i < BJ * (N_D / 4); i += 256) {
            int row = i >> 5;
            int kq = i & 31;
            *(float4*)&Bsh[row][kq << 2] =
                *(const float4*)&emb[(size_t)(jt + row) * N_D + (kq << 2)];
        }
        if (tid < BJ) {
            int g = jt + tid;
            labB[tid] = flag64 ? lab32[2 * g] : lab32[g];
        }
        __syncthreads();

        float acc[4][4] = {};
        #pragma unroll 4
        for (int k = 0; k < N_D; k += 4) {
            float4 a[4], b[4];
            #pragma unroll
            for (int r = 0; r < 4; ++r) a[r] = *(const float4*)&Ash[ty + 16 * r][k];
            #pragma unroll
            for (int c = 0; c < 4; ++c) b[c] = *(const float4*)&Bsh[tx + 16 * c][k];
            #pragma unroll
            for (int r = 0; r < 4; ++r)
                #pragma unroll
                for (int c = 0; c < 4; ++c) {
                    acc[r][c] = fmaf(a[r].x, b[c].x, acc[r][c]);
                    acc[r][c] = fmaf(a[r].y, b[c].y, acc[r][c]);
                    acc[r][c] = fmaf(a[r].z, b[c].z, acc[r][c]);
                    acc[r][c] = fmaf(a[r].w, b[c].w, acc[r][c]);
                }
        }

        #pragma unroll
        for (int c = 0; c < 4; ++c) {
            int lc = tx + 16 * c;
            int gc = jt + lc;
            int lb = labB[lc];
            #pragma unroll
            for (int r = 0; r < 4; ++r) {
                int gr = rowbase + ty + 16 * r;
                float sim = acc[r][c] * (1.0f / 0.07f);
                if (gr != gc) {
                    se[r] += __expf(sim);
                    if (labR[r] == lb) { ps[r] += sim; pc[r] += 1.0f; }
                }
            }
        }
    }

    // reduce across the 16 tx lanes (contiguous lanes within a wave)
    #pragma unroll
    for (int off = 1; off < 16; off <<= 1) {
        #pragma unroll
        for (int r = 0; r < 4; ++r) {
            se[r] += __shfl_xor(se[r], off);
            ps[r] += __shfl_xor(ps[r], off);
            pc[r] += __shfl_xor(pc[r], off);
        }
    }
    if (tx == 0) {
        #pragma unroll
        for (int r = 0; r < 4; ++r) {
            int gr = rowbase + ty + 16 * r;
            atomicAdd(&ws[gr], se[r]);
            atomicAdd(&ws[N + gr], ps[r]);
            atomicAdd(&ws[2 * N + gr], pc[r]);
        }
    }
}

__global__ void k_final(const float* __restrict__ ws, float* __restrict__ out, int N) {
    __shared__ float red[256];
    float local = 0.0f;
    for (int i = threadIdx.x; i < N; i += 256) {
        float sev = ws[i], psv = ws[N + i], pcv = ws[2 * N + i];
        float lp = psv - pcv * logf(sev + 1e-9f);
        float denom = (pcv == 0.0f) ? 1.0f : pcv;
        local += lp / denom;
    }
    red[threadIdx.x] = local;
    __syncthreads();
    for (int s = 128; s > 0; s >>= 1) {
        if (threadIdx.x < s) red[threadIdx.x] += red[threadIdx.x + s];
        __syncthreads();
    }
    if (threadIdx.x == 0) out[0] = -red[0] / (float)N;
}

extern "C" void kernel_launch(void* const* d_in, const int* in_sizes, int n_in,
                              void* d_out, int out_size, void* d_ws, size_t ws_size,
                              hipStream_t stream) {
    const float* emb = (const float*)d_in[0];
    const int* lab = (const int*)d_in[1];
    float* out = (float*)d_out;
    float* ws = (float*)d_ws;
    const int N = in_sizes[1];              // 8192

    hipLaunchKernelGGL(k_prep, dim3(32), dim3(256), 0, stream, lab, ws, N);
    dim3 grid(N / BI, NSPLIT);
    hipLaunchKernelGGL(k_main, grid, dim3(256), 0, stream, emb, lab, ws, N);
    hipLaunchKernelGGL(k_final, dim3(1), dim3(256), 0, stream, ws, out, N);
}

// Round 2
// 83.442 us; speedup vs baseline: 3.5588x; 3.5588x over previous
//
#include <hip/hip_runtime.h>
#include <hip/hip_bf16.h>
#include <math.h>

#define N_D 128
#define BI 128          // rows per block
#define BJ 64           // cols per tile iteration
#define NSPLIT 8        // column-range splits -> grid 64x8 = 512 blocks
#define TEMP_INV 14.285714285714286f   // 1/0.07

using bf16x8 = __attribute__((ext_vector_type(8))) short;
using f32x4  = __attribute__((ext_vector_type(4))) float;

// ws layout (floats): [0,N) sumexp | [N,2N) possum | [2N,3N) poscnt | [3N] int flag (labels int64?)

__device__ __forceinline__ ushort f2bf(float f) {
    __hip_bfloat16 h = __float2bfloat16(f);
    return *reinterpret_cast<ushort*>(&h);
}

__global__ void k_prep(const int* __restrict__ lab32, float* __restrict__ ws, int N) {
    int tid = blockIdx.x * blockDim.x + threadIdx.x;
    int total = 3 * N;
    for (int i = tid; i < total; i += gridDim.x * blockDim.x) ws[i] = 0.0f;
    if (blockIdx.x == 0) {
        __shared__ int nz;
        if (threadIdx.x == 0) nz = 0;
        __syncthreads();
        int local = 0;
        int half = N >> 1;
        for (int i = threadIdx.x; i < half; i += blockDim.x)
            if (lab32[2 * i + 1] != 0) local = 1;
        if (local) atomicOr(&nz, 1);
        __syncthreads();
        if (threadIdx.x == 0) ((int*)ws)[3 * N] = (nz == 0) ? 1 : 0;
    }
}

__global__ __launch_bounds__(256) void k_main(const float* __restrict__ emb,
                                              const int* __restrict__ lab32,
                                              float* __restrict__ ws, int N) {
    __shared__ ushort Ash[BI * N_D];   // 32 KB, XOR-swizzled
    __shared__ ushort Bsh[BJ * N_D];   // 16 KB, XOR-swizzled
    __shared__ int labA[BI];
    __shared__ int labB[BJ];

    const int tid  = threadIdx.x;
    const int lane = tid & 63;
    const int wave = tid >> 6;
    const int wr = wave >> 1;          // 2x2 wave grid: 64-row x 32-col per wave
    const int wc = wave & 1;
    const int l15 = lane & 15;
    const int lhi = lane >> 4;
    const int rowbase  = blockIdx.x * BI;
    const int colsPer  = N / NSPLIT;
    const int colstart = blockIdx.y * colsPer;
    const int flag64 = ((const int*)ws)[3 * N];

    // ---- stage A tile: 128 rows x 128, f32 -> bf16, swizzled LDS ----
    for (int id = tid; id < BI * 32; id += 256) {
        int row = id >> 5, k4 = id & 31;
        float4 v = *(const float4*)&emb[(size_t)(rowbase + row) * N_D + (k4 << 2)];
        uint p0 = (uint)f2bf(v.x) | ((uint)f2bf(v.y) << 16);
        uint p1 = (uint)f2bf(v.z) | ((uint)f2bf(v.w) << 16);
        int byte = (row << 8) + (k4 << 3);
        byte ^= (row & 7) << 4;
        *(uint2*)((char*)Ash + byte) = make_uint2(p0, p1);
    }
    if (tid < BI) {
        int g = rowbase + tid;
        labA[tid] = flag64 ? lab32[2 * g] : lab32[g];
    }
    __syncthreads();

    int labR[4][4];
    const int rowc = rowbase + wr * 64 + lhi * 4;   // + rf*16 + reg = global row
    #pragma unroll
    for (int rf = 0; rf < 4; ++rf)
        #pragma unroll
        for (int reg = 0; reg < 4; ++reg)
            labR[rf][reg] = labA[wr * 64 + rf * 16 + lhi * 4 + reg];

    float se[4][4], ps[4][4], pc[4][4];
    #pragma unroll
    for (int rf = 0; rf < 4; ++rf)
        #pragma unroll
        for (int reg = 0; reg < 4; ++reg) { se[rf][reg] = 0.f; ps[rf][reg] = 0.f; pc[rf][reg] = 0.f; }

    for (int jt = colstart; jt < colstart + colsPer; jt += BJ) {
        __syncthreads();   // previous iter's readers done
        // ---- stage B tile: 64 rows x 128 ----
        for (int id = tid; id < BJ * 32; id += 256) {
            int row = id >> 5, k4 = id & 31;
            float4 v = *(const float4*)&emb[(size_t)(jt + row) * N_D + (k4 << 2)];
            uint p0 = (uint)f2bf(v.x) | ((uint)f2bf(v.y) << 16);
            uint p1 = (uint)f2bf(v.z) | ((uint)f2bf(v.w) << 16);
            int byte = (row << 8) + (k4 << 3);
            byte ^= (row & 7) << 4;
            *(uint2*)((char*)Bsh + byte) = make_uint2(p0, p1);
        }
        if (tid < BJ) {
            int g = jt + tid;
            labB[tid] = flag64 ? lab32[2 * g] : lab32[g];
        }
        __syncthreads();

        // ---- MFMA: wave computes 64x32 via 4x2 fragments of 16x16, K=128 ----
        f32x4 zero4 = {0.f, 0.f, 0.f, 0.f};
        f32x4 acc[4][2];
        #pragma unroll
        for (int rf = 0; rf < 4; ++rf)
            #pragma unroll
            for (int cf = 0; cf < 2; ++cf) acc[rf][cf] = zero4;

        const int kbyteBase = lhi * 16;
        #pragma unroll
        for (int ks = 0; ks < 4; ++ks) {
            int kb = ks * 64 + kbyteBase;
            bf16x8 aF[4], bF[2];
            #pragma unroll
            for (int rf = 0; rf < 4; ++rf) {
                int row = wr * 64 + rf * 16 + l15;
                int byte = (row << 8) + kb;
                byte ^= (row & 7) << 4;
                aF[rf] = *(bf16x8*)((char*)Ash + byte);
            }
            #pragma unroll
            for (int cf = 0; cf < 2; ++cf) {
                int col = wc * 32 + cf * 16 + l15;
                int byte = (col << 8) + kb;
                byte ^= (col & 7) << 4;
                bF[cf] = *(bf16x8*)((char*)Bsh + byte);
            }
            #pragma unroll
            for (int rf = 0; rf < 4; ++rf)
                #pragma unroll
                for (int cf = 0; cf < 2; ++cf)
                    acc[rf][cf] = __builtin_amdgcn_mfma_f32_16x16x32_bf16(
                        aF[rf], bF[cf], acc[rf][cf], 0, 0, 0);
        }

        // ---- fused epilogue ----
        int labC[2], gcol[2];
        #pragma unroll
        for (int cf = 0; cf < 2; ++cf) {
            int col = wc * 32 + cf * 16 + l15;
            labC[cf] = labB[col];
            gcol[cf] = jt + col;
        }
        bool hasdiag = (jt < rowbase + BI) && (jt + BJ > rowbase);

#define EPILOGUE(HD)                                                          \
        _Pragma("unroll")                                                     \
        for (int cf = 0; cf < 2; ++cf) {                                      \
            _Pragma("unroll")                                                 \
            for (int rf = 0; rf < 4; ++rf) {                                  \
                _Pragma("unroll")                                             \
                for (int reg = 0; reg < 4; ++reg) {                           \
                    float sim = acc[rf][cf][reg] * TEMP_INV;                  \
                    float e = __expf(sim);                                    \
                    bool pos = (labR[rf][reg] == labC[cf]);                   \
                    if (HD) {                                                 \
                        bool diag = ((rowc + rf * 16 + reg) == gcol[cf]);     \
                        e = diag ? 0.f : e;                                   \
                        pos = pos && !diag;                                   \
                    }                                                         \
                    se[rf][reg] += e;                                         \
                    ps[rf][reg] += pos ? sim : 0.f;                           \
                    pc[rf][reg] += pos ? 1.f : 0.f;                           \
                }                                                             \
            }                                                                 \
        }

        if (hasdiag) { EPILOGUE(true) } else { EPILOGUE(false) }
#undef EPILOGUE
    }

    // ---- reduce across the 16 lanes sharing the same row set ----
    for (int m = 1; m < 16; m <<= 1) {
        #pragma unroll
        for (int rf = 0; rf < 4; ++rf)
            #pragma unroll
            for (int reg = 0; reg < 4; ++reg) {
                se[rf][reg] += __shfl_xor(se[rf][reg], m);
                ps[rf][reg] += __shfl_xor(ps[rf][reg], m);
                pc[rf][reg] += __shfl_xor(pc[rf][reg], m);
            }
    }
    if (l15 == 0) {
        #pragma unroll
        for (int rf = 0; rf < 4; ++rf)
            #pragma unroll
            for (int reg = 0; reg < 4; ++reg) {
                int row = rowc + rf * 16 + reg;
                atomicAdd(&ws[row],         se[rf][reg]);
                atomicAdd(&ws[N + row],     ps[rf][reg]);
                atomicAdd(&ws[2 * N + row], pc[rf][reg]);
            }
    }
}

__global__ void k_final(const float* __restrict__ ws, float* __restrict__ out, int N) {
    __shared__ float red[256];
    float local = 0.0f;
    for (int i = threadIdx.x; i < N; i += 256) {
        float sev = ws[i], psv = ws[N + i], pcv = ws[2 * N + i];
        float lp = psv - pcv * logf(sev + 1e-9f);
        float denom = (pcv == 0.0f) ? 1.0f : pcv;
        local += lp / denom;
    }
    red[threadIdx.x] = local;
    __syncthreads();
    for (int s = 128; s > 0; s >>= 1) {
        if (threadIdx.x < s) red[threadIdx.x] += red[threadIdx.x + s];
        __syncthreads();
    }
    if (threadIdx.x == 0) out[0] = -red[0] / (float)N;
}

extern "C" void kernel_launch(void* const* d_in, const int* in_sizes, int n_in,
                              void* d_out, int out_size, void* d_ws, size_t ws_size,
                              hipStream_t stream) {
    const float* emb = (const float*)d_in[0];
    const int* lab = (const int*)d_in[1];
    float* out = (float*)d_out;
    float* ws = (float*)d_ws;
    const int N = in_sizes[1];   // 8192

    hipLaunchKernelGGL(k_prep, dim3(32), dim3(256), 0, stream, lab, ws, N);
    dim3 grid(N / BI, NSPLIT);
    hipLaunchKernelGGL(k_main, grid, dim3(256), 0, stream, emb, lab, ws, N);
    hipLaunchKernelGGL(k_final, dim3(1), dim3(256), 0, stream, ws, out, N);
}

// Round 3
// 77.023 us; speedup vs baseline: 3.8553x; 1.0833x over previous
//
#include <hip/hip_runtime.h>
#include <hip/hip_bf16.h>
#include <math.h>

#define N_D 128
#define TEMP_INV 14.285714285714286f
#define EXP2_SCALE 20.60992915555662f   // (1/0.07) * log2(e)

using bf16x8 = __attribute__((ext_vector_type(8))) short;
using f32x4  = __attribute__((ext_vector_type(4))) float;

// ---------------- new-path ws layout (bytes), N=8192 only ----------------
#define EBF_OFF   0u                     // 8192*128 bf16, PRE-SWIZZLED rows (2 MB)
#define SE_OFF    2097152u               // 8192 f32 row exp-sums
#define S_OFF     2129920u               // 100*128 f32 class sums
#define CNT_OFF   2181120u               // 100 f32 class counts
#define SPART_OFF 2181632u               // 64 partials * 51200 B
#define NPART     64
#define SPART_SZ  51200u
#define FLAG_OFF  (SPART_OFF + NPART * SPART_SZ)   // int: labels-are-int64 flag
#define FIN_OFF   (FLAG_OFF + 4u)                  // f32 final accumulator
#define WS_NEEDED (FIN_OFF + 4u)

__device__ __forceinline__ ushort f2bf(float f) {
    __hip_bfloat16 h = __float2bfloat16(f);
    return *reinterpret_cast<ushort*>(&h);
}

__device__ __forceinline__ void glds16(const void* src, void* dst) {
    __builtin_amdgcn_global_load_lds(
        (const __attribute__((address_space(1))) unsigned int*)src,
        (__attribute__((address_space(3))) unsigned int*)dst, 16, 0, 0);
}

__device__ int detect_i64(const int* lab, int N) {
    __shared__ int s_any;
    if (threadIdx.x == 0) s_any = 0;
    __syncthreads();
    int any = 0;
    for (int i = threadIdx.x; i < (N >> 1); i += blockDim.x)
        any |= (lab[2 * i + 1] != 0);
    if (__any(any) && (threadIdx.x & 63) == 0) atomicOr(&s_any, 1);
    __syncthreads();
    return s_any ? 0 : 1;   // all odd words zero => int64
}

// ============ k_pre: bf16 convert (pre-swizzled) + class-sum partials + hist/zero ============
__global__ __launch_bounds__(256) void k_pre(const float* __restrict__ emb,
                                             const int* __restrict__ lab,
                                             char* __restrict__ ws, int N) {
    __shared__ float Ssh[2][100][N_D];   // 102.4 KB
    __shared__ int Chist[100];
    const int blk = blockIdx.x;
    const int tid = threadIdx.x;

    if (blk < 512) {
        // convert: slot id -> row g, slot s; store orig[g][s ^ (g&15)] at [g][s]
        int id = blk * 256 + tid;            // 0 .. 131071
        int g = id >> 4, s = id & 15;
        int srcslot = s ^ (g & 15);
        const float* src = emb + (size_t)g * N_D + srcslot * 8;
        float4 v0 = *(const float4*)src;
        float4 v1 = *(const float4*)(src + 4);
        uint4 o;
        o.x = (uint)f2bf(v0.x) | ((uint)f2bf(v0.y) << 16);
        o.y = (uint)f2bf(v0.z) | ((uint)f2bf(v0.w) << 16);
        o.z = (uint)f2bf(v1.x) | ((uint)f2bf(v1.y) << 16);
        o.w = (uint)f2bf(v1.z) | ((uint)f2bf(v1.w) << 16);
        ((uint4*)(ws + EBF_OFF))[id] = o;
        return;
    }
    if (blk < 512 + NPART) {
        // class-sum partial over 128 rows, two independent LDS streams
        int p = blk - 512;
        int flag64 = detect_i64(lab, N);
        for (int i = tid; i < 2 * 100 * N_D; i += 256) ((float*)Ssh)[i] = 0.f;
        __syncthreads();
        int base = p * 128;
        int stream = tid >> 7;      // 0/1
        int d = tid & 127;
        for (int r = 0; r < 64; ++r) {
            int row = base + r * 2 + stream;
            int L = flag64 ? lab[2 * row] : lab[row];
            Ssh[stream][L][d] += emb[(size_t)row * N_D + d];
        }
        __syncthreads();
        float* Sp = (float*)(ws + SPART_OFF + (size_t)p * SPART_SZ);
        for (int i = tid; i < 100 * N_D; i += 256)
            Sp[i] = ((float*)Ssh)[i] + ((float*)Ssh)[100 * N_D + i];
        return;
    }
    // last block: flag, label histogram, zero se + fin
    {
        int flag64 = detect_i64(lab, N);
        for (int i = tid; i < 100; i += 256) Chist[i] = 0;
        __syncthreads();
        for (int i = tid; i < N; i += 256) {
            int L = flag64 ? lab[2 * i] : lab[i];
            atomicAdd(&Chist[L], 1);
        }
        __syncthreads();
        for (int i = tid; i < 100; i += 256)
            ((float*)(ws + CNT_OFF))[i] = (float)Chist[i];
        float* se = (float*)(ws + SE_OFF);
        for (int i = tid; i < N; i += 256) se[i] = 0.f;
        if (tid == 0) {
            *(int*)(ws + FLAG_OFF) = flag64;
            *(float*)(ws + FIN_OFF) = 0.f;
        }
    }
}

// ============ k_reduceS: sum the 64 class-sum partials ============
__global__ __launch_bounds__(256) void k_reduceS(char* __restrict__ ws) {
    int id = blockIdx.x * 256 + threadIdx.x;   // grid 50 -> 12800
    if (id < 100 * N_D) {
        float s = 0.f;
        for (int p = 0; p < NPART; ++p)
            s += ((const float*)(ws + SPART_OFF + (size_t)p * SPART_SZ))[id];
        ((float*)(ws + S_OFF))[id] = s;
    }
}

// ============ k_main: bf16 MFMA GEMM + fused exp row-sum ============
__global__ __launch_bounds__(256) void k_main(char* __restrict__ ws, int N) {
    __shared__ __attribute__((aligned(128))) char smem[65536];  // A: [0,32K), B: [32K,64K)

    const char* ebf = ws + EBF_OFF;
    float* se_ws = (float*)(ws + SE_OFF);

    const int flat = blockIdx.x;           // 512 blocks
    const int split = flat & 7;            // -> XCD id under round-robin
    const int rowblk = flat >> 3;
    const int rowbase = rowblk * 128;
    const int colstart = split * (N >> 3); // 1024-wide column panel

    const int tid = threadIdx.x;
    const int lane = tid & 63;
    const int wave = tid >> 6;
    const int wr = wave >> 1, wc = wave & 1;
    const int l15 = lane & 15, lhi = lane >> 4;

    // ---- stage A (128 x 256B = 32 KB), 8 glds per wave ----
    {
        const char* srcbase = ebf + ((size_t)(rowbase + wave * 32 + lhi) << 8) + (l15 << 4);
        char* dstbase = smem + (wave * 32) * 256;
        #pragma unroll
        for (int i = 0; i < 8; ++i)
            glds16(srcbase + i * 1024, dstbase + i * 1024);
    }

    float se[4][4];
    #pragma unroll
    for (int rf = 0; rf < 4; ++rf)
        #pragma unroll
        for (int reg = 0; reg < 4; ++reg) se[rf][reg] = 0.f;

    const int iters = (N >> 3) >> 7;   // 8
    for (int it = 0; it < iters; ++it) {
        const int jt = colstart + it * 128;
        __syncthreads();   // prev compute done (and A-drain on iter 0)
        {
            const char* srcbase = ebf + ((size_t)(jt + wave * 32 + lhi) << 8) + (l15 << 4);
            char* dstbase = smem + 32768 + (wave * 32) * 256;
            #pragma unroll
            for (int i = 0; i < 8; ++i)
                glds16(srcbase + i * 1024, dstbase + i * 1024);
        }
        __syncthreads();   // drains vmcnt -> tiles ready

        f32x4 acc[4][4];
        #pragma unroll
        for (int rf = 0; rf < 4; ++rf)
            #pragma unroll
            for (int cf = 0; cf < 4; ++cf) acc[rf][cf] = (f32x4){0.f, 0.f, 0.f, 0.f};

        #pragma unroll
        for (int ks = 0; ks < 4; ++ks) {
            const int kb = (ks * 64 + lhi * 16) ^ (l15 << 4);
            bf16x8 aF[4], bF[4];
            #pragma unroll
            for (int rf = 0; rf < 4; ++rf) {
                int row = wr * 64 + rf * 16 + l15;
                aF[rf] = *(const bf16x8*)(smem + row * 256 + kb);
            }
            #pragma unroll
            for (int cf = 0; cf < 4; ++cf) {
                int col = wc * 64 + cf * 16 + l15;
                bF[cf] = *(const bf16x8*)(smem + 32768 + col * 256 + kb);
            }
            #pragma unroll
            for (int rf = 0; rf < 4; ++rf)
                #pragma unroll
                for (int cf = 0; cf < 4; ++cf)
                    acc[rf][cf] = __builtin_amdgcn_mfma_f32_16x16x32_bf16(
                        aF[rf], bF[cf], acc[rf][cf], 0, 0, 0);
        }

        if (jt == rowbase) {   // diagonal tile: mask self-similarity
            #pragma unroll
            for (int rf = 0; rf < 4; ++rf)
                #pragma unroll
                for (int cf = 0; cf < 4; ++cf)
                    #pragma unroll
                    for (int reg = 0; reg < 4; ++reg) {
                        int lrow = wr * 64 + rf * 16 + lhi * 4 + reg;
                        int lcol = wc * 64 + cf * 16 + l15;
                        float e = exp2f(acc[rf][cf][reg] * EXP2_SCALE);
                        se[rf][reg] += (lrow == lcol) ? 0.f : e;
                    }
        } else {
            #pragma unroll
            for (int rf = 0; rf < 4; ++rf)
                #pragma unroll
                for (int cf = 0; cf < 4; ++cf)
                    #pragma unroll
                    for (int reg = 0; reg < 4; ++reg)
                        se[rf][reg] += exp2f(acc[rf][cf][reg] * EXP2_SCALE);
        }
    }

    // reduce over the 16 column-lanes, then one atomic per row
    #pragma unroll
    for (int m = 1; m < 16; m <<= 1)
        #pragma unroll
        for (int rf = 0; rf < 4; ++rf)
            #pragma unroll
            for (int reg = 0; reg < 4; ++reg)
                se[rf][reg] += __shfl_xor(se[rf][reg], m);
    if (l15 == 0) {
        #pragma unroll
        for (int rf = 0; rf < 4; ++rf)
            #pragma unroll
            for (int reg = 0; reg < 4; ++reg) {
                int row = rowbase + wr * 64 + rf * 16 + lhi * 4 + reg;
                atomicAdd(&se_ws[row], se[rf][reg]);
            }
    }
}

// ============ k_rowfinal: per-row analytic pos-sum + combine ============
__global__ __launch_bounds__(256) void k_rowfinal(const float* __restrict__ emb,
                                                  const int* __restrict__ lab,
                                                  char* __restrict__ ws, int N) {
    __shared__ float red[256];
    const int r = blockIdx.x * 256 + threadIdx.x;
    const int flag64 = *(const int*)(ws + FLAG_OFF);
    float contrib = 0.f;
    if (r < N) {
        int L = flag64 ? lab[2 * r] : lab[r];
        const float* Sr = (const float*)(ws + S_OFF) + L * N_D;
        const float* er = emb + (size_t)r * N_D;
        float dot = 0.f, nrm = 0.f;
        #pragma unroll 4
        for (int k = 0; k < N_D; k += 4) {
            float4 e = *(const float4*)(er + k);
            float4 s = *(const float4*)(Sr + k);
            dot += e.x * s.x + e.y * s.y + e.z * s.z + e.w * s.w;
            nrm += e.x * e.x + e.y * e.y + e.z * e.z + e.w * e.w;
        }
        float pc = ((const float*)(ws + CNT_OFF))[L] - 1.f;
        float sev = ((const float*)(ws + SE_OFF))[r];
        if (pc > 0.f) {
            float ps = (dot - nrm) * TEMP_INV;   // sum of positive sims, self removed
            contrib = (ps - pc * logf(sev + 1e-9f)) / pc;
        }
    }
    red[threadIdx.x] = contrib;
    __syncthreads();
    for (int s = 128; s > 0; s >>= 1) {
        if (threadIdx.x < s) red[threadIdx.x] += red[threadIdx.x + s];
        __syncthreads();
    }
    if (threadIdx.x == 0) atomicAdd((float*)(ws + FIN_OFF), red[0]);
}

__global__ void k_out(char* __restrict__ ws, float* __restrict__ out, int N) {
    out[0] = -(*(const float*)(ws + FIN_OFF)) / (float)N;
}

// ======================= fallback (round-2 proven path) =======================
#define FBI 128
#define FBJ 64
#define FNSPLIT 8

__global__ void fb_prep(const int* __restrict__ lab32, float* __restrict__ ws, int N) {
    int tid = blockIdx.x * blockDim.x + threadIdx.x;
    int total = 3 * N;
    for (int i = tid; i < total; i += gridDim.x * blockDim.x) ws[i] = 0.0f;
    if (blockIdx.x == 0) {
        __shared__ int nz;
        if (threadIdx.x == 0) nz = 0;
        __syncthreads();
        int local = 0;
        int half = N >> 1;
        for (int i = threadIdx.x; i < half; i += blockDim.x)
            if (lab32[2 * i + 1] != 0) local = 1;
        if (local) atomicOr(&nz, 1);
        __syncthreads();
        if (threadIdx.x == 0) ((int*)ws)[3 * N] = (nz == 0) ? 1 : 0;
    }
}

__global__ __launch_bounds__(256) void fb_main(const float* __restrict__ emb,
                                               const int* __restrict__ lab32,
                                               float* __restrict__ ws, int N) {
    __shared__ ushort Ash[FBI * N_D];
    __shared__ ushort Bsh[FBJ * N_D];
    __shared__ int labA[FBI];
    __shared__ int labB[FBJ];

    const int tid  = threadIdx.x;
    const int lane = tid & 63;
    const int wave = tid >> 6;
    const int wr = wave >> 1;
    const int wc = wave & 1;
    const int l15 = lane & 15;
    const int lhi = lane >> 4;
    const int rowbase  = blockIdx.x * FBI;
    const int colsPer  = N / FNSPLIT;
    const int colstart = blockIdx.y * colsPer;
    const int flag64 = ((const int*)ws)[3 * N];

    for (int id = tid; id < FBI * 32; id += 256) {
        int row = id >> 5, k4 = id & 31;
        float4 v = *(const float4*)&emb[(size_t)(rowbase + row) * N_D + (k4 << 2)];
        uint p0 = (uint)f2bf(v.x) | ((uint)f2bf(v.y) << 16);
        uint p1 = (uint)f2bf(v.z) | ((uint)f2bf(v.w) << 16);
        int byte = (row << 8) + (k4 << 3);
        byte ^= (row & 7) << 4;
        *(uint2*)((char*)Ash + byte) = make_uint2(p0, p1);
    }
    if (tid < FBI) {
        int g = rowbase + tid;
        labA[tid] = flag64 ? lab32[2 * g] : lab32[g];
    }
    __syncthreads();

    int labR[4][4];
    const int rowc = rowbase + wr * 64 + lhi * 4;
    #pragma unroll
    for (int rf = 0; rf < 4; ++rf)
        #pragma unroll
        for (int reg = 0; reg < 4; ++reg)
            labR[rf][reg] = labA[wr * 64 + rf * 16 + lhi * 4 + reg];

    float se[4][4], ps[4][4], pc[4][4];
    #pragma unroll
    for (int rf = 0; rf < 4; ++rf)
        #pragma unroll
        for (int reg = 0; reg < 4; ++reg) { se[rf][reg] = 0.f; ps[rf][reg] = 0.f; pc[rf][reg] = 0.f; }

    for (int jt = colstart; jt < colstart + colsPer; jt += FBJ) {
        __syncthreads();
        for (int id = tid; id < FBJ * 32; id += 256) {
            int row = id >> 5, k4 = id & 31;
            float4 v = *(const float4*)&emb[(size_t)(jt + row) * N_D + (k4 << 2)];
            uint p0 = (uint)f2bf(v.x) | ((uint)f2bf(v.y) << 16);
            uint p1 = (uint)f2bf(v.z) | ((uint)f2bf(v.w) << 16);
            int byte = (row << 8) + (k4 << 3);
            byte ^= (row & 7) << 4;
            *(uint2*)((char*)Bsh + byte) = make_uint2(p0, p1);
        }
        if (tid < FBJ) {
            int g = jt + tid;
            labB[tid] = flag64 ? lab32[2 * g] : lab32[g];
        }
        __syncthreads();

        f32x4 zero4 = {0.f, 0.f, 0.f, 0.f};
        f32x4 acc[4][2];
        #pragma unroll
        for (int rf = 0; rf < 4; ++rf)
            #pragma unroll
            for (int cf = 0; cf < 2; ++cf) acc[rf][cf] = zero4;

        const int kbyteBase = lhi * 16;
        #pragma unroll
        for (int ks = 0; ks < 4; ++ks) {
            int kb = ks * 64 + kbyteBase;
            bf16x8 aF[4], bF[2];
            #pragma unroll
            for (int rf = 0; rf < 4; ++rf) {
                int row = wr * 64 + rf * 16 + l15;
                int byte = (row << 8) + kb;
                byte ^= (row & 7) << 4;
                aF[rf] = *(bf16x8*)((char*)Ash + byte);
            }
            #pragma unroll
            for (int cf = 0; cf < 2; ++cf) {
                int col = wc * 32 + cf * 16 + l15;
                int byte = (col << 8) + kb;
                byte ^= (col & 7) << 4;
                bF[cf] = *(bf16x8*)((char*)Bsh + byte);
            }
            #pragma unroll
            for (int rf = 0; rf < 4; ++rf)
                #pragma unroll
                for (int cf = 0; cf < 2; ++cf)
                    acc[rf][cf] = __builtin_amdgcn_mfma_f32_16x16x32_bf16(
                        aF[rf], bF[cf], acc[rf][cf], 0, 0, 0);
        }

        int labC[2], gcol[2];
        #pragma unroll
        for (int cf = 0; cf < 2; ++cf) {
            int col = wc * 32 + cf * 16 + l15;
            labC[cf] = labB[col];
            gcol[cf] = jt + col;
        }
        bool hasdiag = (jt < rowbase + FBI) && (jt + FBJ > rowbase);

#define EPILOGUE(HD)                                                          \
        _Pragma("unroll")                                                     \
        for (int cf = 0; cf < 2; ++cf) {                                      \
            _Pragma("unroll")                                                 \
            for (int rf = 0; rf < 4; ++rf) {                                  \
                _Pragma("unroll")                                             \
                for (int reg = 0; reg < 4; ++reg) {                           \
                    float sim = acc[rf][cf][reg] * TEMP_INV;                  \
                    float e = __expf(sim);                                    \
                    bool pos = (labR[rf][reg] == labC[cf]);                   \
                    if (HD) {                                                 \
                        bool diag = ((rowc + rf * 16 + reg) == gcol[cf]);     \
                        e = diag ? 0.f : e;                                   \
                        pos = pos && !diag;                                   \
                    }                                                         \
                    se[rf][reg] += e;                                         \
                    ps[rf][reg] += pos ? sim : 0.f;                           \
                    pc[rf][reg] += pos ? 1.f : 0.f;                           \
                }                                                             \
            }                                                                 \
        }

        if (hasdiag) { EPILOGUE(true) } else { EPILOGUE(false) }
#undef EPILOGUE
    }

    for (int m = 1; m < 16; m <<= 1) {
        #pragma unroll
        for (int rf = 0; rf < 4; ++rf)
            #pragma unroll
            for (int reg = 0; reg < 4; ++reg) {
                se[rf][reg] += __shfl_xor(se[rf][reg], m);
                ps[rf][reg] += __shfl_xor(ps[rf][reg], m);
                pc[rf][reg] += __shfl_xor(pc[rf][reg], m);
            }
    }
    if (l15 == 0) {
        #pragma unroll
        for (int rf = 0; rf < 4; ++rf)
            #pragma unroll
            for (int reg = 0; reg < 4; ++reg) {
                int row = rowc + rf * 16 + reg;
                atomicAdd(&ws[row],         se[rf][reg]);
                atomicAdd(&ws[N + row],     ps[rf][reg]);
                atomicAdd(&ws[2 * N + row], pc[rf][reg]);
            }
    }
}

__global__ void fb_final(const float* __restrict__ ws, float* __restrict__ out, int N) {
    __shared__ float red[256];
    float local = 0.0f;
    for (int i = threadIdx.x; i < N; i += 256) {
        float sev = ws[i], psv = ws[N + i], pcv = ws[2 * N + i];
        float lp = psv - pcv * logf(sev + 1e-9f);
        float denom = (pcv == 0.0f) ? 1.0f : pcv;
        local += lp / denom;
    }
    red[threadIdx.x] = local;
    __syncthreads();
    for (int s = 128; s > 0; s >>= 1) {
        if (threadIdx.x < s) red[threadIdx.x] += red[threadIdx.x + s];
        __syncthreads();
    }
    if (threadIdx.x == 0) out[0] = -red[0] / (float)N;
}

// ======================= launcher =======================
extern "C" void kernel_launch(void* const* d_in, const int* in_sizes, int n_in,
                              void* d_out, int out_size, void* d_ws, size_t ws_size,
                              hipStream_t stream) {
    const float* emb = (const float*)d_in[0];
    const int* lab = (const int*)d_in[1];
    float* out = (float*)d_out;
    const int N = in_sizes[0] / N_D;

    if (N == 8192 && ws_size >= (size_t)WS_NEEDED) {
        char* ws = (char*)d_ws;
        hipLaunchKernelGGL(k_pre, dim3(512 + NPART + 1), dim3(256), 0, stream, emb, lab, ws, N);
        hipLaunchKernelGGL(k_reduceS, dim3(50), dim3(256), 0, stream, ws);
        hipLaunchKernelGGL(k_main, dim3(512), dim3(256), 0, stream, ws, N);
        hipLaunchKernelGGL(k_rowfinal, dim3(32), dim3(256), 0, stream, emb, lab, ws, N);
        hipLaunchKernelGGL(k_out, dim3(1), dim3(1), 0, stream, ws, out, N);
    } else {
        float* ws = (float*)d_ws;
        hipLaunchKernelGGL(fb_prep, dim3(32), dim3(256), 0, stream, lab, ws, N);
        dim3 grid(N / FBI, FNSPLIT);
        hipLaunchKernelGGL(fb_main, grid, dim3(256), 0, stream, emb, lab, ws, N);
        hipLaunchKernelGGL(fb_final, dim3(1), dim3(256), 0, stream, ws, out, N);
    }
}

// Round 4
// 71.778 us; speedup vs baseline: 4.1370x; 1.0731x over previous
//
#include <hip/hip_runtime.h>
#include <hip/hip_bf16.h>
#include <math.h>

#define N_D 128
#define TEMP_INV 14.285714285714286f
#define EXP2_SCALE 20.60992915555662f   // (1/0.07) * log2(e)

using bf16x8 = __attribute__((ext_vector_type(8))) short;
using f32x4  = __attribute__((ext_vector_type(4))) float;

// ---------------- ws layout (bytes), N=8192 fast path ----------------
#define EBF_OFF   0u                     // 8192*128 bf16, PRE-SWIZZLED rows (2 MB)
#define SE_OFF    2097152u               // 8192 f32 row exp-sums
#define S_OFF     2129920u               // 100*128 f32 class sums
#define CNT_OFF   2181120u               // 100 f32 class counts (pad to 512B)
#define SPART_OFF 2181632u               // 64 partials * 51712 B (S 51200 + cnt 400 + pad)
#define NPART     64
#define SPART_SZ  51712u
#define FLAG_OFF  (SPART_OFF + NPART * SPART_SZ)
#define FIN_OFF   (FLAG_OFF + 4u)
#define CTR_OFF   (FLAG_OFF + 8u)
#define WS_NEEDED (FLAG_OFF + 12u)

__device__ __forceinline__ ushort f2bf(float f) {
    __hip_bfloat16 h = __float2bfloat16(f);
    return *reinterpret_cast<ushort*>(&h);
}

__device__ __forceinline__ void glds16(const void* src, void* dst) {
    __builtin_amdgcn_global_load_lds(
        (const __attribute__((address_space(1))) unsigned int*)src,
        (__attribute__((address_space(3))) unsigned int*)dst, 16, 0, 0);
}

__device__ int detect_i64(const int* lab, int N) {
    __shared__ int s_any;
    if (threadIdx.x == 0) s_any = 0;
    __syncthreads();
    int any = 0;
    for (int i = threadIdx.x; i < (N >> 1); i += blockDim.x)
        any |= (lab[2 * i + 1] != 0);
    if (__any(any) && (threadIdx.x & 63) == 0) atomicOr(&s_any, 1);
    __syncthreads();
    return s_any ? 0 : 1;   // all odd words zero => int64
}

// ============ k_pre: bf16 convert (pre-swizzled) + class-sum/hist partials + misc ============
__global__ __launch_bounds__(256) void k_pre(const float* __restrict__ emb,
                                             const int* __restrict__ lab,
                                             char* __restrict__ ws, int N) {
    __shared__ float Ssh[2][100][N_D];   // 102.4 KB
    __shared__ int hloc[100];
    const int blk = blockIdx.x;
    const int tid = threadIdx.x;

    if (blk < 512) {
        // convert: slot id -> row g, slot s; store orig[g][s ^ (g&15)] at [g][s]
        int id = blk * 256 + tid;            // 0 .. 131071
        int g = id >> 4, s = id & 15;
        int srcslot = s ^ (g & 15);
        const float* src = emb + (size_t)g * N_D + srcslot * 8;
        float4 v0 = *(const float4*)src;
        float4 v1 = *(const float4*)(src + 4);
        uint4 o;
        o.x = (uint)f2bf(v0.x) | ((uint)f2bf(v0.y) << 16);
        o.y = (uint)f2bf(v0.z) | ((uint)f2bf(v0.w) << 16);
        o.z = (uint)f2bf(v1.x) | ((uint)f2bf(v1.y) << 16);
        o.w = (uint)f2bf(v1.z) | ((uint)f2bf(v1.w) << 16);
        ((uint4*)(ws + EBF_OFF))[id] = o;
        return;
    }
    if (blk < 512 + NPART) {
        // class-sum partial over 128 rows, 2 streams x 64 rows, prefetched
        int p = blk - 512;
        int flag64 = detect_i64(lab, N);
        for (int i = tid; i < 2 * 100 * N_D; i += 256) ((float*)Ssh)[i] = 0.f;
        for (int i = tid; i < 100; i += 256) hloc[i] = 0;
        __syncthreads();
        int base = p * 128;
        int stream = tid >> 7;      // 0/1
        int d = tid & 127;
        int row0 = base + stream;
        float v = emb[(size_t)row0 * N_D + d];
        int L = flag64 ? lab[2 * row0] : lab[row0];
        for (int r = 0; r < 64; ++r) {
            float vn = 0.f; int Ln = 0;
            if (r < 63) {
                int rw = base + (r + 1) * 2 + stream;
                vn = emb[(size_t)rw * N_D + d];
                Ln = flag64 ? lab[2 * rw] : lab[rw];
            }
            Ssh[stream][L][d] += v;
            if (d == 0) atomicAdd(&hloc[L], 1);
            v = vn; L = Ln;
        }
        __syncthreads();
        float* Sp = (float*)(ws + SPART_OFF + (size_t)p * SPART_SZ);
        for (int i = tid; i < 100 * N_D; i += 256)
            Sp[i] = ((float*)Ssh)[i] + ((float*)Ssh)[100 * N_D + i];
        for (int i = tid; i < 100; i += 256)
            Sp[100 * N_D + i] = (float)hloc[i];
        return;
    }
    // misc block: flag, zero se/fin/ctr
    {
        int flag64 = detect_i64(lab, N);
        float* se = (float*)(ws + SE_OFF);
        for (int i = tid; i < N; i += 256) se[i] = 0.f;
        if (tid == 0) {
            *(int*)(ws + FLAG_OFF) = flag64;
            *(float*)(ws + FIN_OFF) = 0.f;
            *(int*)(ws + CTR_OFF) = 0;
        }
    }
}

// ============ k_reduceS: sum the partials (S + counts) ============
__global__ __launch_bounds__(256) void k_reduceS(char* __restrict__ ws) {
    int id = blockIdx.x * 256 + threadIdx.x;   // grid 51 -> 13056, need 12900
    if (id < 100 * N_D + 100) {
        float s = 0.f;
        #pragma unroll 4
        for (int p = 0; p < NPART; ++p)
            s += ((const float*)(ws + SPART_OFF + (size_t)p * SPART_SZ))[id];
        if (id < 100 * N_D) ((float*)(ws + S_OFF))[id] = s;
        else                ((float*)(ws + CNT_OFF))[id - 100 * N_D] = s;
    }
}

// ============ k_main: A-in-regs, B double-buffered 2-phase pipeline ============
__global__ __launch_bounds__(256, 2) void k_main(char* __restrict__ ws, int N) {
    __shared__ __attribute__((aligned(128))) char smem[65536];  // buf0 [0,32K) / buf1 [32K,64K)

    const char* ebf = ws + EBF_OFF;
    float* se_ws = (float*)(ws + SE_OFF);

    const int flat = blockIdx.x;           // 512 blocks
    const int split = flat & 7;            // XCD id under round-robin
    const int rowblk = flat >> 3;
    const int rowbase = rowblk * 128;
    const int colstart = split * (N >> 3); // 1024-wide column panel

    const int tid = threadIdx.x;
    const int lane = tid & 63;
    const int wave = tid >> 6;
    const int wr = wave >> 1, wc = wave & 1;
    const int l15 = lane & 15, lhi = lane >> 4;

    // wave-uniform staging bases (glds: per-lane LDS offset is implicit lane*16)
    const int stageRowOff = wave * 32 + lhi;     // + 4*i per glds
    const int stageByteOff = l15 << 4;

    // ---- 1. stage A (128 x 256B = 32 KB) into buf0 ----
    {
        const char* srcbase = ebf + ((size_t)(rowbase + stageRowOff) << 8) + stageByteOff;
        char* dstbase = smem + (wave * 32) * 256;
        #pragma unroll
        for (int i = 0; i < 8; ++i)
            glds16(srcbase + i * 1024, dstbase + i * 1024);
    }
    __syncthreads();

    // ---- 2. hoist A fragments to registers ----
    bf16x8 aF[4][4];   // [rf][ks]
    #pragma unroll
    for (int rf = 0; rf < 4; ++rf) {
        int row = wr * 64 + rf * 16 + l15;
        #pragma unroll
        for (int ks = 0; ks < 4; ++ks) {
            int kb = (ks * 64 + lhi * 16) ^ (l15 << 4);
            aF[rf][ks] = *(const bf16x8*)(smem + row * 256 + kb);
        }
    }
    // ---- 3. stage B(0) into buf1 ----
    {
        const char* srcbase = ebf + ((size_t)(colstart + stageRowOff) << 8) + stageByteOff;
        char* dstbase = smem + 32768 + (wave * 32) * 256;
        #pragma unroll
        for (int i = 0; i < 8; ++i)
            glds16(srcbase + i * 1024, dstbase + i * 1024);
    }
    __syncthreads();   // A-frag reads done (buf0 free), B(0) resident

    float se[4][4];
    #pragma unroll
    for (int rf = 0; rf < 4; ++rf)
        #pragma unroll
        for (int reg = 0; reg < 4; ++reg) se[rf][reg] = 0.f;

    #pragma unroll
    for (int t = 0; t < 8; ++t) {
        const int jt = colstart + t * 128;
        const char* cur = (t & 1) ? smem : smem + 32768;   // B(t)
        char* nxt = (t & 1) ? smem + 32768 : smem;         // B(t+1) dest
        // issue next-tile stage first (overlaps with compute below)
        if (t < 7) {
            const char* srcbase = ebf + ((size_t)(jt + 128 + stageRowOff) << 8) + stageByteOff;
            char* dstbase = nxt + (wave * 32) * 256;
            #pragma unroll
            for (int i = 0; i < 8; ++i)
                glds16(srcbase + i * 1024, dstbase + i * 1024);
        }

        f32x4 acc[4][4];
        #pragma unroll
        for (int rf = 0; rf < 4; ++rf)
            #pragma unroll
            for (int cf = 0; cf < 4; ++cf) acc[rf][cf] = (f32x4){0.f, 0.f, 0.f, 0.f};

        #pragma unroll
        for (int ks = 0; ks < 4; ++ks) {
            const int kb = (ks * 64 + lhi * 16) ^ (l15 << 4);
            bf16x8 bF[4];
            #pragma unroll
            for (int cf = 0; cf < 4; ++cf) {
                int col = wc * 64 + cf * 16 + l15;
                bF[cf] = *(const bf16x8*)(cur + col * 256 + kb);
            }
            #pragma unroll
            for (int rf = 0; rf < 4; ++rf)
                #pragma unroll
                for (int cf = 0; cf < 4; ++cf)
                    acc[rf][cf] = __builtin_amdgcn_mfma_f32_16x16x32_bf16(
                        aF[rf][ks], bF[cf], acc[rf][cf], 0, 0, 0);
        }

        if (jt == rowbase) {   // diagonal tile: mask self-similarity
            #pragma unroll
            for (int rf = 0; rf < 4; ++rf)
                #pragma unroll
                for (int cf = 0; cf < 4; ++cf)
                    #pragma unroll
                    for (int reg = 0; reg < 4; ++reg) {
                        int lrow = wr * 64 + rf * 16 + lhi * 4 + reg;
                        int lcol = wc * 64 + cf * 16 + l15;
                        float e = exp2f(acc[rf][cf][reg] * EXP2_SCALE);
                        se[rf][reg] += (lrow == lcol) ? 0.f : e;
                    }
        } else {
            #pragma unroll
            for (int rf = 0; rf < 4; ++rf)
                #pragma unroll
                for (int cf = 0; cf < 4; ++cf)
                    #pragma unroll
                    for (int reg = 0; reg < 4; ++reg)
                        se[rf][reg] += exp2f(acc[rf][cf][reg] * EXP2_SCALE);
        }
        __syncthreads();   // drains glds (next tile ready) + all waves done with cur
    }

    // reduce over the 16 column-lanes, then one atomic per row
    #pragma unroll
    for (int m = 1; m < 16; m <<= 1)
        #pragma unroll
        for (int rf = 0; rf < 4; ++rf)
            #pragma unroll
            for (int reg = 0; reg < 4; ++reg)
                se[rf][reg] += __shfl_xor(se[rf][reg], m);
    if (l15 == 0) {
        #pragma unroll
        for (int rf = 0; rf < 4; ++rf)
            #pragma unroll
            for (int reg = 0; reg < 4; ++reg) {
                int row = rowbase + wr * 64 + rf * 16 + lhi * 4 + reg;
                atomicAdd(&se_ws[row], se[rf][reg]);
            }
    }
}

// ============ k_rowfinal: per-row analytic pos-sum + combine + write out ============
__global__ __launch_bounds__(256) void k_rowfinal(const float* __restrict__ emb,
                                                  const int* __restrict__ lab,
                                                  char* __restrict__ ws,
                                                  float* __restrict__ out, int N) {
    __shared__ float red[256];
    const int r = blockIdx.x * 256 + threadIdx.x;
    const int flag64 = *(const int*)(ws + FLAG_OFF);
    float contrib = 0.f;
    if (r < N) {
        int L = flag64 ? lab[2 * r] : lab[r];
        const float* Sr = (const float*)(ws + S_OFF) + L * N_D;
        const float* er = emb + (size_t)r * N_D;
        float dot = 0.f, nrm = 0.f;
        #pragma unroll 4
        for (int k = 0; k < N_D; k += 4) {
            float4 e = *(const float4*)(er + k);
            float4 s = *(const float4*)(Sr + k);
            dot += e.x * s.x + e.y * s.y + e.z * s.z + e.w * s.w;
            nrm += e.x * e.x + e.y * e.y + e.z * e.z + e.w * e.w;
        }
        float pc = ((const float*)(ws + CNT_OFF))[L] - 1.f;
        float sev = ((const float*)(ws + SE_OFF))[r];
        if (pc > 0.f) {
            float ps = (dot - nrm) * TEMP_INV;
            contrib = (ps - pc * logf(sev + 1e-9f)) / pc;
        }
    }
    red[threadIdx.x] = contrib;
    __syncthreads();
    for (int s = 128; s > 0; s >>= 1) {
        if (threadIdx.x < s) red[threadIdx.x] += red[threadIdx.x + s];
        __syncthreads();
    }
    if (threadIdx.x == 0) {
        atomicAdd((float*)(ws + FIN_OFF), red[0]);
        __threadfence();
        int done = atomicAdd((int*)(ws + CTR_OFF), 1);
        if (done == (int)gridDim.x - 1) {
            float fin = atomicAdd((float*)(ws + FIN_OFF), 0.0f);  // device-scope read
            out[0] = -fin / (float)N;
        }
    }
}

// ======================= fallback (round-2 proven path) =======================
#define FBI 128
#define FBJ 64
#define FNSPLIT 8

__global__ void fb_prep(const int* __restrict__ lab32, float* __restrict__ ws, int N) {
    int tid = blockIdx.x * blockDim.x + threadIdx.x;
    int total = 3 * N;
    for (int i = tid; i < total; i += gridDim.x * blockDim.x) ws[i] = 0.0f;
    if (blockIdx.x == 0) {
        __shared__ int nz;
        if (threadIdx.x == 0) nz = 0;
        __syncthreads();
        int local = 0;
        int half = N >> 1;
        for (int i = threadIdx.x; i < half; i += blockDim.x)
            if (lab32[2 * i + 1] != 0) local = 1;
        if (local) atomicOr(&nz, 1);
        __syncthreads();
        if (threadIdx.x == 0) ((int*)ws)[3 * N] = (nz == 0) ? 1 : 0;
    }
}

__global__ __launch_bounds__(256) void fb_main(const float* __restrict__ emb,
                                               const int* __restrict__ lab32,
                                               float* __restrict__ ws, int N) {
    __shared__ ushort Ash[FBI * N_D];
    __shared__ ushort Bsh[FBJ * N_D];
    __shared__ int labA[FBI];
    __shared__ int labB[FBJ];

    const int tid  = threadIdx.x;
    const int lane = tid & 63;
    const int wave = tid >> 6;
    const int wr = wave >> 1;
    const int wc = wave & 1;
    const int l15 = lane & 15;
    const int lhi = lane >> 4;
    const int rowbase  = blockIdx.x * FBI;
    const int colsPer  = N / FNSPLIT;
    const int colstart = blockIdx.y * colsPer;
    const int flag64 = ((const int*)ws)[3 * N];

    for (int id = tid; id < FBI * 32; id += 256) {
        int row = id >> 5, k4 = id & 31;
        float4 v = *(const float4*)&emb[(size_t)(rowbase + row) * N_D + (k4 << 2)];
        uint p0 = (uint)f2bf(v.x) | ((uint)f2bf(v.y) << 16);
        uint p1 = (uint)f2bf(v.z) | ((uint)f2bf(v.w) << 16);
        int byte = (row << 8) + (k4 << 3);
        byte ^= (row & 7) << 4;
        *(uint2*)((char*)Ash + byte) = make_uint2(p0, p1);
    }
    if (tid < FBI) {
        int g = rowbase + tid;
        labA[tid] = flag64 ? lab32[2 * g] : lab32[g];
    }
    __syncthreads();

    int labR[4][4];
    const int rowc = rowbase + wr * 64 + lhi * 4;
    #pragma unroll
    for (int rf = 0; rf < 4; ++rf)
        #pragma unroll
        for (int reg = 0; reg < 4; ++reg)
            labR[rf][reg] = labA[wr * 64 + rf * 16 + lhi * 4 + reg];

    float se[4][4], ps[4][4], pc[4][4];
    #pragma unroll
    for (int rf = 0; rf < 4; ++rf)
        #pragma unroll
        for (int reg = 0; reg < 4; ++reg) { se[rf][reg] = 0.f; ps[rf][reg] = 0.f; pc[rf][reg] = 0.f; }

    for (int jt = colstart; jt < colstart + colsPer; jt += FBJ) {
        __syncthreads();
        for (int id = tid; id < FBJ * 32; id += 256) {
            int row = id >> 5, k4 = id & 31;
            float4 v = *(const float4*)&emb[(size_t)(jt + row) * N_D + (k4 << 2)];
            uint p0 = (uint)f2bf(v.x) | ((uint)f2bf(v.y) << 16);
            uint p1 = (uint)f2bf(v.z) | ((uint)f2bf(v.w) << 16);
            int byte = (row << 8) + (k4 << 3);
            byte ^= (row & 7) << 4;
            *(uint2*)((char*)Bsh + byte) = make_uint2(p0, p1);
        }
        if (tid < FBJ) {
            int g = jt + tid;
            labB[tid] = flag64 ? lab32[2 * g] : lab32[g];
        }
        __syncthreads();

        f32x4 zero4 = {0.f, 0.f, 0.f, 0.f};
        f32x4 acc[4][2];
        #pragma unroll
        for (int rf = 0; rf < 4; ++rf)
            #pragma unroll
            for (int cf = 0; cf < 2; ++cf) acc[rf][cf] = zero4;

        const int kbyteBase = lhi * 16;
        #pragma unroll
        for (int ks = 0; ks < 4; ++ks) {
            int kb = ks * 64 + kbyteBase;
            bf16x8 aF[4], bF[2];
            #pragma unroll
            for (int rf = 0; rf < 4; ++rf) {
                int row = wr * 64 + rf * 16 + l15;
                int byte = (row << 8) + kb;
                byte ^= (row & 7) << 4;
                aF[rf] = *(bf16x8*)((char*)Ash + byte);
            }
            #pragma unroll
            for (int cf = 0; cf < 2; ++cf) {
                int col = wc * 32 + cf * 16 + l15;
                int byte = (col << 8) + kb;
                byte ^= (col & 7) << 4;
                bF[cf] = *(bf16x8*)((char*)Bsh + byte);
            }
            #pragma unroll
            for (int rf = 0; rf < 4; ++rf)
                #pragma unroll
                for (int cf = 0; cf < 2; ++cf)
                    acc[rf][cf] = __builtin_amdgcn_mfma_f32_16x16x32_bf16(
                        aF[rf], bF[cf], acc[rf][cf], 0, 0, 0);
        }

        int labC[2], gcol[2];
        #pragma unroll
        for (int cf = 0; cf < 2; ++cf) {
            int col = wc * 32 + cf * 16 + l15;
            labC[cf] = labB[col];
            gcol[cf] = jt + col;
        }
        bool hasdiag = (jt < rowbase + FBI) && (jt + FBJ > rowbase);

#define EPILOGUE(HD)                                                          \
        _Pragma("unroll")                                                     \
        for (int cf = 0; cf < 2; ++cf) {                                      \
            _Pragma("unroll")                                                 \
            for (int rf = 0; rf < 4; ++rf) {                                  \
                _Pragma("unroll")                                             \
                for (int reg = 0; reg < 4; ++reg) {                           \
                    float sim = acc[rf][cf][reg] * TEMP_INV;                  \
                    float e = __expf(sim);                                    \
                    bool pos = (labR[rf][reg] == labC[cf]);                   \
                    if (HD) {                                                 \
                        bool diag = ((rowc + rf * 16 + reg) == gcol[cf]);     \
                        e = diag ? 0.f : e;                                   \
                        pos = pos && !diag;                                   \
                    }                                                         \
                    se[rf][reg] += e;                                         \
                    ps[rf][reg] += pos ? sim : 0.f;                           \
                    pc[rf][reg] += pos ? 1.f : 0.f;                           \
                }                                                             \
            }                                                                 \
        }

        if (hasdiag) { EPILOGUE(true) } else { EPILOGUE(false) }
#undef EPILOGUE
    }

    for (int m = 1; m < 16; m <<= 1) {
        #pragma unroll
        for (int rf = 0; rf < 4; ++rf)
            #pragma unroll
            for (int reg = 0; reg < 4; ++reg) {
                se[rf][reg] += __shfl_xor(se[rf][reg], m);
                ps[rf][reg] += __shfl_xor(ps[rf][reg], m);
                pc[rf][reg] += __shfl_xor(pc[rf][reg], m);
            }
    }
    if (l15 == 0) {
        #pragma unroll
        for (int rf = 0; rf < 4; ++rf)
            #pragma unroll
            for (int reg = 0; reg < 4; ++reg) {
                int row = rowc + rf * 16 + reg;
                atomicAdd(&ws[row],         se[rf][reg]);
                atomicAdd(&ws[N + row],     ps[rf][reg]);
                atomicAdd(&ws[2 * N + row], pc[rf][reg]);
            }
    }
}

__global__ void fb_final(const float* __restrict__ ws, float* __restrict__ out, int N) {
    __shared__ float red[256];
    float local = 0.0f;
    for (int i = threadIdx.x; i < N; i += 256) {
        float sev = ws[i], psv = ws[N + i], pcv = ws[2 * N + i];
        float lp = psv - pcv * logf(sev + 1e-9f);
        float denom = (pcv == 0.0f) ? 1.0f : pcv;
        local += lp / denom;
    }
    red[threadIdx.x] = local;
    __syncthreads();
    for (int s = 128; s > 0; s >>= 1) {
        if (threadIdx.x < s) red[threadIdx.x] += red[threadIdx.x + s];
        __syncthreads();
    }
    if (threadIdx.x == 0) out[0] = -red[0] / (float)N;
}

// ======================= launcher =======================
extern "C" void kernel_launch(void* const* d_in, const int* in_sizes, int n_in,
                              void* d_out, int out_size, void* d_ws, size_t ws_size,
                              hipStream_t stream) {
    const float* emb = (const float*)d_in[0];
    const int* lab = (const int*)d_in[1];
    float* out = (float*)d_out;
    const int N = in_sizes[0] / N_D;

    if (N == 8192 && ws_size >= (size_t)WS_NEEDED) {
        char* ws = (char*)d_ws;
        hipLaunchKernelGGL(k_pre, dim3(512 + NPART + 1), dim3(256), 0, stream, emb, lab, ws, N);
        hipLaunchKernelGGL(k_reduceS, dim3(51), dim3(256), 0, stream, ws);
        hipLaunchKernelGGL(k_main, dim3(512), dim3(256), 0, stream, ws, N);
        hipLaunchKernelGGL(k_rowfinal, dim3(32), dim3(256), 0, stream, emb, lab, ws, out, N);
    } else {
        float* ws = (float*)d_ws;
        hipLaunchKernelGGL(fb_prep, dim3(32), dim3(256), 0, stream, lab, ws, N);
        dim3 grid(N / FBI, FNSPLIT);
        hipLaunchKernelGGL(fb_main, grid, dim3(256), 0, stream, emb, lab, ws, N);
        hipLaunchKernelGGL(fb_final, dim3(1), dim3(256), 0, stream, ws, out, N);
    }
}